// Round 15
// baseline (2788.319 us; speedup 1.0000x reference)
//
#include <hip/hip_runtime.h>
#include <hip/hip_bf16.h>
#include <math.h>

// ============================================================================
// ResponseFilter — round 17: phased GEMM (m218 double-barrier interleave).
//
// r11-r16: MfmaUtil pinned 21-27% for every tile/wave/buffer/occupancy
// variant -> phases serialize (m233). Only untried lever: the per-phase
// {reads, stage, barrier, MFMA-burst(setprio), barrier} interleave with
// counted vmcnt (m218: coarse counted-vmcnt alone is null; the fine
// interleave is the gain). This round: r14's race-audited skeleton
// (256x128, 256thr, 4 waves 2Mx2N, wave 128x64 acc[8][4], BK=32,
// 3 buffers 72KB -> 2 blocks/CU, (256,2) 96 VGPR no-spill) restructured
// into 2 barrier-bounded phases per K-tile; stage targets buf (k+2)%3
// (read-free during k); vmcnt(6) at phase 2 waits only tile k+1 (k+2's 6
// loads cross the barrier in flight — true T4).
// Everything else byte-identical to round 12 (best: 2574us, absmax 0).
// ============================================================================

#define B_  16
#define T_  32
#define L_  64
#define D_  768
#define H_  12
#define F_  2048
#define ZR_ 100
#define NP_ 512
#define EPS_ 1e-5f

// meta int offsets (d_ws as int*)
#define MI_NTOT  0
#define MI_NRESP 8
#define MI_OFF   32
#define MI_BIDX  64
#define MI_TIDX  576
#define MI_NODE  1088

// ws float offsets
#define WS_BIAS2 2048
#define WS_EMEAN 34816
#define WS_S     428032
#define WS_WST   428544    // pe/pd padded bf16 weights + padded pe bias
#define WS_BIG   1313280   // bf16 QKV/hidden region; bf16 Z overlay

#define PEB_F    (WS_WST + 196608)   // float offset of padded pe bias [256]

// d_out float offsets (flat tuple: oh[512], ext_mask[32768], n_ext_adv[1],
// new_tree_lens[16], new_emb[25165824], new_msk[32768])
#define OUT_OH   0
#define OUT_EXT  512
#define OUT_NEA  33280
#define OUT_NTL  33281
#define OUT_NEMB 33297
#define OUT_NMSK 25199121
#define OUT_XSCR 33300      // bf16 X scratch, 32768*768 ushorts (ends 12616212)
#define OUT_WSTK 12616224   // bf16 converted weights, 4 passes x 5,505,024 ushorts

// per-pass converted-weight segment sizes (ushorts)
#define WSEG0 1769472   // qkv  [2304][768]
#define WSEG1 589824    // out  [768][768]
#define WSEG2 1572864   // w1   [2048][768]
#define WSEG3 1572864   // w2   [768][2048]
#define WPASS 5505024

typedef __attribute__((ext_vector_type(8))) short short8;
typedef __attribute__((ext_vector_type(4))) float f32x4;

__device__ inline float bf2f(unsigned s) {
  return __uint_as_float((s & 0xffffu) << 16);
}
__device__ inline unsigned short f2bf(float x) {
  unsigned u = __float_as_uint(x);
  u += 0x7fffu + ((u >> 16) & 1u);      // round-to-nearest-even
  return (unsigned short)(u >> 16);
}
__device__ inline unsigned pack2(float a, float b) {
  return (unsigned)f2bf(a) | ((unsigned)f2bf(b) << 16);
}

// ---------------------------------------------------------------------------
__global__ void meta_kernel(const int* __restrict__ tl, int* __restrict__ mi) {
  if (threadIdx.x != 0) return;
  int off = 0;
  for (int b = 0; b < B_; b++) {
    int nr = tl[b] - 1;
    mi[MI_NRESP + b] = nr;
    mi[MI_OFF + b] = off;
    off += nr;
  }
  mi[MI_NTOT] = off;
  for (int j = 0; j < NP_; j++) {
    int b = -1, t = 0;
    if (j < off) {
      b = 0;
      while (b + 1 < B_ && j >= mi[MI_OFF + b + 1]) b++;
      t = j - mi[MI_OFF + b] + 1;
    }
    mi[MI_BIDX + j] = b;
    mi[MI_TIDX + j] = t;
  }
}

// ---------------------------------------------------------------------------
// batched fp32 -> bf16 conversion of one layer-pass's 4 weight matrices.
// grid = WPASS/1024 blocks; segment boundaries are multiples of 1024.
__global__ __launch_bounds__(256) void w2bf4_kernel(
    const float* __restrict__ s0, const float* __restrict__ s1,
    const float* __restrict__ s2, const float* __restrict__ s3,
    unsigned short* __restrict__ dst) {
  const int e = blockIdx.x * 1024 + threadIdx.x * 4;
  const float* src;
  int off;
  if (e < WSEG0)                         { src = s0; off = e; }
  else if (e < WSEG0 + WSEG1)            { src = s1; off = e - WSEG0; }
  else if (e < WSEG0 + WSEG1 + WSEG2)    { src = s2; off = e - WSEG0 - WSEG1; }
  else                                   { src = s3; off = e - WSEG0 - WSEG1 - WSEG2; }
  float4 v = *(const float4*)(src + off);
  uint2 pk; pk.x = pack2(v.x, v.y); pk.y = pack2(v.z, v.w);
  *(uint2*)(dst + e) = pk;
}

// ---------------------------------------------------------------------------
// pe_w [100][768] -> peW [256][768] bf16 (rows >=100 zero)
// pd_w [768][100] -> pdW [768][256] bf16 (cols >=100 zero)
// pe_b [100]      -> peB [256] fp32 (zero-padded)
__global__ __launch_bounds__(256) void pepd_stage(
    const float* __restrict__ pew, const float* __restrict__ peb,
    const float* __restrict__ pdw,
    unsigned short* __restrict__ dpe, unsigned short* __restrict__ dpd,
    float* __restrict__ dpeb) {
  const int blk = blockIdx.x, t = threadIdx.x;
  if (blk < 192) {                       // pe: 196608 elems
    const int e = blk * 1024 + t * 4;
    const int r = e / 768, c = e % 768;
    float v[4];
    #pragma unroll
    for (int j = 0; j < 4; j++) v[j] = (r < ZR_) ? pew[r * 768 + c + j] : 0.f;
    uint2 pk; pk.x = pack2(v[0], v[1]); pk.y = pack2(v[2], v[3]);
    *(uint2*)(dpe + e) = pk;
  } else if (blk < 384) {                // pd: 196608 elems
    const int e = (blk - 192) * 1024 + t * 4;
    const int r = e / 256, c = e % 256;
    float v[4];
    #pragma unroll
    for (int j = 0; j < 4; j++) v[j] = (c + j < ZR_) ? pdw[r * ZR_ + c + j] : 0.f;
    uint2 pk; pk.x = pack2(v[0], v[1]); pk.y = pack2(v[2], v[3]);
    *(uint2*)(dpd + e) = pk;
  } else {                               // bias pad
    dpeb[t] = (t < ZR_) ? peb[t] : 0.f;
  }
}

// ---------------------------------------------------------------------------
// X[j,l,:] bf16 = reply embedding (zero for padded j); bias2 = mask or -1e30
__global__ __launch_bounds__(192) void gather_kernel(
    const float* __restrict__ emb, const float* __restrict__ am,
    const int* __restrict__ mi, unsigned short* __restrict__ X,
    float* __restrict__ bias2) {
  const int blk = blockIdx.x;          // j*64 + l
  const int j = blk >> 6, l = blk & 63;
  const int ntot = mi[MI_NTOT];
  const int t = threadIdx.x;
  float4 v = make_float4(0.f, 0.f, 0.f, 0.f);
  if (j < ntot) {
    const int b = mi[MI_BIDX + j], tt = mi[MI_TIDX + j];
    v = ((const float4*)(emb + (size_t)((b * T_ + tt) * L_ + l) * D_))[t];
    if (t == 0) bias2[blk] = am[(b * T_ + tt) * L_ + l];
  } else {
    if (t == 0) bias2[blk] = -1e30f;
  }
  uint2 pk; pk.x = pack2(v.x, v.y); pk.y = pack2(v.z, v.w);
  *(uint2*)(X + (size_t)blk * D_ + t * 4) = pk;
}

// ---------------------------------------------------------------------------
// zero QKV rows >= ntot*64 in BIG (once per launch): attention reads K/V for
// all 512 padded responses; rows beyond the last GEMM tile must be finite.
__global__ __launch_bounds__(256) void zerotail_kernel(const int* __restrict__ mi,
                                                       unsigned short* __restrict__ BIG) {
  const int row = blockIdx.x;                 // 0 .. 32767
  if (row < mi[MI_NTOT] * 64) return;
  uint4 z = make_uint4(0u, 0u, 0u, 0u);
  uint4* p = (uint4*)(BIG + (size_t)row * 2304);   // 2304 ushorts = 288 uint4
  for (int c = threadIdx.x; c < 288; c += 256) p[c] = z;
}

// ---------------------------------------------------------------------------
__global__ __launch_bounds__(256) void emean_kernel(const unsigned short* __restrict__ X,
                                                    float* __restrict__ em) {
  const int j = blockIdx.x;
  int d = threadIdx.x;
  for (int c = 0; c < 3; c++, d += 256) {
    const unsigned short* p = X + (size_t)j * L_ * D_ + d;
    float s = 0.f;
    for (int l = 0; l < L_; l++) s += bf2f(p[l * D_]);
    em[j * D_ + d] = s * (1.f / 64.f);
  }
}

// ---------------------------------------------------------------------------
__device__ inline float blockSum256(float v, float* red) {
  #pragma unroll
  for (int o = 32; o > 0; o >>= 1) v += __shfl_down(v, o);
  const int lane = threadIdx.x & 63, wid = threadIdx.x >> 6;
  __syncthreads();
  if (lane == 0) red[wid] = v;
  __syncthreads();
  return red[0] + red[1] + red[2] + red[3];
}

// in-place LN (bf16 storage, fp32 stats); skips padded rows
__global__ __launch_bounds__(256) void ln_kernel(unsigned short* __restrict__ X,
                                                 const float* __restrict__ g,
                                                 const float* __restrict__ bb,
                                                 const int* __restrict__ mi) {
  const int row = blockIdx.x;
  if (row >= mi[MI_NTOT] * L_) return;
  unsigned short* p = X + (size_t)row * D_;
  const int t = threadIdx.x;
  __shared__ float red[4];
  float v0 = bf2f(p[t]), v1 = bf2f(p[t + 256]), v2 = bf2f(p[t + 512]);
  float s = blockSum256(v0 + v1 + v2, red);
  float m = s * (1.f / 768.f);
  float d0 = v0 - m, d1 = v1 - m, d2 = v2 - m;
  float q = blockSum256(d0 * d0 + d1 * d1 + d2 * d2, red);
  float r = rsqrtf(q * (1.f / 768.f) + EPS_);
  p[t]       = f2bf(d0 * r * g[t]       + bb[t]);
  p[t + 256] = f2bf(d1 * r * g[t + 256] + bb[t + 256]);
  p[t + 512] = f2bf(d2 * r * g[t + 512] + bb[t + 512]);
}

// ---------------------------------------------------------------------------
// MFMA bf16 GEMM: C[M,N] = [C +] act(A @ W^T + bias). 256x128 tile, 256 thr
// (4 waves 2Mx2N; wave = 128x64 via 8x4 of 16x16x32 MFMA), BK=32, TRIPLE
// buffer (72 KB -> 2 blocks/CU). TWO barrier-bounded phases per K-tile:
//   ph1: read B(4)+A m0-3(4); stage half of tile k+2 (3 loads, buf (k+2)%3,
//        read-free during k); s_barrier; setprio+16 MFMA; s_barrier.
//   ph2: read A m4-7(4); stage other half (3); vmcnt(6) [waits tile k+1
//        only — k+2's 6 loads cross the barrier in flight]; s_barrier;
//        setprio+16 MFMA; s_barrier.
// launch_bounds(256,2): r14-measured 96 VGPR, no spill.
// Launch grid 128*CT (CT = N/128); ACTIVE tiles NTa = ceil(rows/256)*CT on
// device; bijective m204 chunk map over NTa (8 XCDs), col-fastest in chunk.
// LDS rows 32 ushorts; 16B group g of row at slot g^((row>>1)&3).
// ACT: 0 none, 1 relu, 2 tanh.
template <int ACT, bool ADD>
__global__ __launch_bounds__(256, 2) void gemm_mfma(
    const unsigned short* __restrict__ A, int lda, int K,
    const unsigned short* __restrict__ W, int ldw,
    const float* __restrict__ bias,
    unsigned short* __restrict__ C, int ldc, int CT,
    const int* __restrict__ mi) {
  const int rows = mi[MI_NTOT] * 64;
  const int RTa = (rows + 255) >> 8;
  const int NTa = RTa * CT;
  const int id = blockIdx.x;
  if (id >= NTa) return;
  // bijective XCD chunk map (m204): xcd k gets a contiguous wg range
  const int q8 = NTa >> 3, r8 = NTa & 7;
  const int xcd = id & 7, idx = id >> 3;
  const int wg = (xcd < r8 ? xcd * (q8 + 1) : r8 * (q8 + 1) + (xcd - r8) * q8) + idx;
  const int row0 = (wg / CT) * 256;
  const int col0 = (wg % CT) * 128;
  __shared__ unsigned short As[3][256 * 32];
  __shared__ unsigned short Bs[3][128 * 32];
  const int t = threadIdx.x;            // 0..255
  const int lane = t & 63, w = t >> 6;  // 4 waves
  const int wr = w >> 1, wc = w & 1;    // 2 x 2 wave grid
  const int quad = lane >> 4, l15 = lane & 15;

  // staging coords (r14-proven): A chunk c = q*256 + t: row = q*64 + (t>>2),
  // slot = t&3; B chunk c = hB*256 + t. gs = (t&3) ^ ((t>>3)&3) (ph-invar).
  const int srow = t >> 2;              // 0..63
  const int sgs = (t & 3) ^ ((t >> 3) & 3);
  const unsigned short* aSrc = A + (size_t)(row0 + srow) * lda + sgs * 8;
  const unsigned short* bSrc = W + (size_t)(col0 + srow) * ldw + sgs * 8;

#define GL_(src, dstbase)                                                       \
  __builtin_amdgcn_global_load_lds(                                             \
      (const __attribute__((address_space(1))) void*)(src),                     \
      (__attribute__((address_space(3))) void*)(dstbase), 16, 0, 0)
  // half 1 of a tile: A quarters 0,1 + B half 0
#define STAGE_H1_(kk, Ad, Bd)                                                   \
  do {                                                                          \
    GL_(aSrc + (kk),                        (Ad) + w * 512);                    \
    GL_(aSrc + (size_t)64 * lda + (kk),     (Ad) + 2048 + w * 512);             \
    GL_(bSrc + (kk),                        (Bd) + w * 512);                    \
  } while (0)
  // half 2: A quarters 2,3 + B half 1
#define STAGE_H2_(kk, Ad, Bd)                                                   \
  do {                                                                          \
    GL_(aSrc + (size_t)128 * lda + (kk),    (Ad) + 4096 + w * 512);             \
    GL_(aSrc + (size_t)192 * lda + (kk),    (Ad) + 6144 + w * 512);             \
    GL_(bSrc + (size_t)64 * ldw + (kk),     (Bd) + 2048 + w * 512);             \
  } while (0)

  auto LDA_ = [&](const unsigned short* buf, int m) -> short8 {
    const int ar = wr * 128 + m * 16 + l15;
    return *(const short8*)(buf + ar * 32 + (quad ^ ((ar >> 1) & 3)) * 8);
  };
  auto LDB_ = [&](const unsigned short* buf, int n) -> short8 {
    const int bn = wc * 64 + n * 16 + l15;
    return *(const short8*)(buf + bn * 32 + (quad ^ ((bn >> 1) & 3)) * 8);
  };

  f32x4 acc[8][4];
  #pragma unroll
  for (int m = 0; m < 8; m++)
    #pragma unroll
    for (int n = 0; n < 4; n++) acc[m][n] = (f32x4){0.f, 0.f, 0.f, 0.f};

  // prologue: stage tiles 0 and 1 (12 loads); vmcnt(6) -> tile 0 landed,
  // tile 1's 6 in flight; barrier.
  STAGE_H1_(0, As[0], Bs[0]);
  STAGE_H2_(0, As[0], Bs[0]);
  STAGE_H1_(32, As[1], Bs[1]);
  STAGE_H2_(32, As[1], Bs[1]);
  __builtin_amdgcn_sched_barrier(0);
  asm volatile("s_waitcnt vmcnt(6)" ::: "memory");
  __builtin_amdgcn_sched_barrier(0);
  __builtin_amdgcn_s_barrier();
  __builtin_amdgcn_sched_barrier(0);

  const int KT = K >> 5;                // >= 8 at all call sites
  for (int kt = 0; kt < KT; ++kt) {
    const unsigned short* Ac = As[kt % 3];
    const unsigned short* Bc = Bs[kt % 3];
    unsigned short* An = As[(kt + 2) % 3];
    unsigned short* Bn = Bs[(kt + 2) % 3];
    const bool m2 = (kt + 2) < KT;
    const int kn = (kt + 2) << 5;
    short8 afr[4], bfr[4];

    // ---- phase 1: m 0-3 ----
    #pragma unroll
    for (int n = 0; n < 4; n++) bfr[n] = LDB_(Bc, n);
    #pragma unroll
    for (int m = 0; m < 4; m++) afr[m] = LDA_(Ac, m);
    if (m2) STAGE_H1_(kn, An, Bn);
    __builtin_amdgcn_sched_barrier(0);
    __builtin_amdgcn_s_barrier();
    __builtin_amdgcn_s_setprio(1);
    #pragma unroll
    for (int m = 0; m < 4; m++)
      #pragma unroll
      for (int n = 0; n < 4; n++)
        acc[m][n] = __builtin_amdgcn_mfma_f32_16x16x32_bf16(afr[m], bfr[n], acc[m][n], 0, 0, 0);
    __builtin_amdgcn_s_setprio(0);
    __builtin_amdgcn_sched_barrier(0);
    __builtin_amdgcn_s_barrier();
    __builtin_amdgcn_sched_barrier(0);

    // ---- phase 2: m 4-7 (bfr reused) ----
    #pragma unroll
    for (int m = 0; m < 4; m++) afr[m] = LDA_(Ac, m + 4);
    if (m2) STAGE_H2_(kn, An, Bn);
    if (kt + 1 < KT) {
      // wait ONLY tile kt+1 (issued a full K-tile ago); kt+2 stays in flight
      __builtin_amdgcn_sched_barrier(0);
      if (m2) asm volatile("s_waitcnt vmcnt(6)" ::: "memory");
      else    asm volatile("s_waitcnt vmcnt(0)" ::: "memory");
      __builtin_amdgcn_sched_barrier(0);
    }
    __builtin_amdgcn_s_barrier();
    __builtin_amdgcn_s_setprio(1);
    #pragma unroll
    for (int m = 0; m < 4; m++)
      #pragma unroll
      for (int n = 0; n < 4; n++)
        acc[m + 4][n] = __builtin_amdgcn_mfma_f32_16x16x32_bf16(afr[m], bfr[n], acc[m + 4][n], 0, 0, 0);
    __builtin_amdgcn_s_setprio(0);
    __builtin_amdgcn_sched_barrier(0);
    __builtin_amdgcn_s_barrier();     // tile kt+1 collectively visible
    __builtin_amdgcn_sched_barrier(0);
  }
#undef STAGE_H1_
#undef STAGE_H2_
#undef GL_

  // epilogue (r12/r14-proven): C/D layout col = lane&15, row = quad*4 + reg
  float bv[4];
  #pragma unroll
  for (int n = 0; n < 4; n++) bv[n] = bias[col0 + wc * 64 + n * 16 + l15];
  #pragma unroll
  for (int m = 0; m < 8; m++) {
    #pragma unroll
    for (int reg = 0; reg < 4; reg++) {
      const size_t cr = (size_t)(row0 + wr * 128 + m * 16 + quad * 4 + reg) * ldc;
      #pragma unroll
      for (int n = 0; n < 4; n++) {
        const int cn = col0 + wc * 64 + n * 16 + l15;
        float x = acc[m][n][reg] + bv[n];
        if (ACT == 1) x = fmaxf(x, 0.f);
        if (ACT == 2) x = tanhf(x);
        if (ADD) x += bf2f(C[cr + cn]);
        C[cr + cn] = f2bf(x);
      }
    }
  }
}

// ---------------------------------------------------------------------------
// Pipelined MFMA flash attention. 1-D grid 3072: id&7 = XCD, then ntp (0..3)
// fastest, lh-chunk slowest -> the blocks sharing one (l,h) K/V slice are
// L2-co-resident on one XCD. 512 threads / 8 waves; block owns 128 q rows;
// wave w owns q rows w*16..w*16+15. SWAPPED QK^T: sa = mfma(K,Q) -> lane
// owns q = l15 with 16 keys local; softmax = local tree + 2 shfl_xor;
// alpha/inv broadcast to oacc rows (q = quad*4+reg) via 4 shfl.
// K dbuf via global_load_lds; V dbuf via reg-staging scatter-late.
__global__ __launch_bounds__(512) void attn_kernel(
    unsigned short* __restrict__ QKV, const float* __restrict__ bias2,
    const int* __restrict__ mi) {
  const int ntot = mi[MI_NTOT];
  const int id = blockIdx.x;
  const int xcd = id & 7, rr = id >> 3;
  const int ntp = rr & 3, lhi = rr >> 2;       // lhi 0..95
  if (ntp * 128 >= ntot) return;
  const int lh = lhi * 8 + xcd;                // 0..767
  const int l = lh / H_, h = lh - l * H_;
  __shared__ unsigned short QPs[128 * 64];  // Q staging, then P (per-wave rows)
  __shared__ unsigned short Ks0[64 * 64], Ks1[64 * 64];
  __shared__ unsigned short Vt0[64 * 64], Vt1[64 * 64];  // V^T [d][key], swizzled
  __shared__ float Bls[512];
  const int t = threadIdx.x;
  const int lane = t & 63, w = t >> 6;      // 8 waves
  const int quad = lane >> 4, l15 = lane & 15;
  const int q0 = ntp * 128;
  const size_t TSTRIDE = (size_t)64 * L_ * 2304;   // elems per 64-key tile

  // K source (1 chunk/thread): row = t>>3 in [0,64), group swizzled
  const int krow = t >> 3;
  const int kgs = (t & 7) ^ (krow & 7);
  const unsigned short* ksrc =
      QKV + (size_t)(krow * L_ + l) * 2304 + 768 + h * 64 + kgs * 8;
  // V source (1 uint4/thread): d-group = w, key = lane
  const unsigned short* vsrc =
      QKV + (size_t)(lane * L_ + l) * 2304 + 1536 + h * 64 + w * 8;

  auto stageK = [&](int mt, unsigned short* Kw) {
    __builtin_amdgcn_global_load_lds(
        (const __attribute__((address_space(1))) void*)(ksrc + (size_t)mt * TSTRIDE),
        (__attribute__((address_space(3))) void*)(Kw + w * 512), 16, 0, 0);
  };
  auto scatterV = [&](uint4 a0, unsigned short* Vw) {
    const unsigned short* p0 = (const unsigned short*)&a0;
    #pragma unroll
    for (int j = 0; j < 8; j++) {
      const int d = w * 8 + j;
      Vw[d * 64 + ((lane >> 3) ^ (d & 7)) * 8 + (lane & 7)] = p0[j];
    }
  };

  // prologue: stage Q (2 chunks/thread) + K0, V0 -> regs, bias -> LDS
  #pragma unroll
  for (int r = 0; r < 2; r++) {
    const int c = r * 512 + t;
    const int row = c >> 3, g = c & 7, gs = g ^ (row & 7);
    const unsigned short* gq =
        QKV + (size_t)((q0 + row) * L_ + l) * 2304 + h * 64 + gs * 8;
    __builtin_amdgcn_global_load_lds(
        (const __attribute__((address_space(1))) void*)gq,
        (__attribute__((address_space(3))) void*)(QPs + r * 4096 + w * 512), 16, 0, 0);
  }
  stageK(0, Ks0);
  uint4 pv0 = *(const uint4*)vsrc;
  Bls[t] = bias2[t * 64 + l];
  __syncthreads();                       // Q,K0 in LDS; pv0 in regs

  // Q fragments (loop-invariant), used as the MFMA B-operand (col = l15)
  const int qrow = w * 16 + l15;         // 0..127
  short8 aq[2];
  #pragma unroll
  for (int kq = 0; kq < 2; kq++)
    aq[kq] = *(const short8*)(QPs + qrow * 64 + ((kq * 4 + quad) ^ (qrow & 7)) * 8);
  scatterV(pv0, Vt0);
  __syncthreads();                       // Vt0 visible; aq read before P reuse

  float runmax = -3.0e38f, runsum = 0.f;
  f32x4 oacc[4];
  #pragma unroll
  for (int i = 0; i < 4; i++) oacc[i] = (f32x4){0.f, 0.f, 0.f, 0.f};

  auto tilecomp = [&](int mt, const unsigned short* Krd, const unsigned short* Vrd) {
    // ---- S^T = K Q^T : sa[n][reg] = S[key=n*16+quad*4+reg][q=l15] ----
    f32x4 sa[4];
    #pragma unroll
    for (int n = 0; n < 4; n++) sa[n] = (f32x4){0.f, 0.f, 0.f, 0.f};
    __builtin_amdgcn_s_setprio(1);
    #pragma unroll
    for (int n = 0; n < 4; n++) {
      const int kr = n * 16 + l15;
      #pragma unroll
      for (int kq = 0; kq < 2; kq++) {
        const short8 bk = *(const short8*)(Krd + kr * 64 + ((kq * 4 + quad) ^ (kr & 7)) * 8);
        sa[n] = __builtin_amdgcn_mfma_f32_16x16x32_bf16(bk, aq[kq], sa[n], 0, 0, 0);
      }
    }
    __builtin_amdgcn_s_setprio(0);
    // bias by key: float4 per n (keys n*16 + quad*4 + 0..3)
    #pragma unroll
    for (int n = 0; n < 4; n++) {
      const float4 bj = *(const float4*)(Bls + mt * 64 + n * 16 + quad * 4);
      sa[n][0] = sa[n][0] * 0.125f + bj.x;
      sa[n][1] = sa[n][1] * 0.125f + bj.y;
      sa[n][2] = sa[n][2] * 0.125f + bj.z;
      sa[n][3] = sa[n][3] * 0.125f + bj.w;
    }

    // ---- online softmax for q = l15: local 16-key tree + 2 shfl ----
    float m16 = -3.0e38f;
    #pragma unroll
    for (int n = 0; n < 4; n++)
      m16 = fmaxf(m16, fmaxf(fmaxf(sa[n][0], sa[n][1]), fmaxf(sa[n][2], sa[n][3])));
    m16 = fmaxf(m16, __shfl_xor(m16, 16));
    m16 = fmaxf(m16, __shfl_xor(m16, 32));
    const float nm = fmaxf(runmax, m16);
    const float alpha = __expf(runmax - nm);
    runmax = nm;
    float s16 = 0.f;
    #pragma unroll
    for (int n = 0; n < 4; n++)
      #pragma unroll
      for (int reg = 0; reg < 4; reg++) {
        const float p = __expf(sa[n][reg] - nm);
        sa[n][reg] = p; s16 += p;
      }
    s16 += __shfl_xor(s16, 16);
    s16 += __shfl_xor(s16, 32);
    runsum = runsum * alpha + s16;
    // broadcast alpha to oacc rows q = quad*4+reg (src lane l15 = that q)
    float al[4];
    #pragma unroll
    for (int reg = 0; reg < 4; reg++)
      al[reg] = __shfl(alpha, (lane & 48) | (quad * 4 + reg));
    #pragma unroll
    for (int dn = 0; dn < 4; dn++)
      #pragma unroll
      for (int reg = 0; reg < 4; reg++) oacc[dn][reg] *= al[reg];

    // ---- P -> LDS bf16 (row qrow = w*16+l15, wave-private) ----
    #pragma unroll
    for (int n = 0; n < 4; n++)
      #pragma unroll
      for (int reg = 0; reg < 4; reg++) {
        const int key = n * 16 + quad * 4 + reg;
        QPs[qrow * 64 + ((key >> 3) ^ (qrow & 7)) * 8 + (key & 7)] = f2bf(sa[n][reg]);
      }
    short8 ap[2];
    #pragma unroll
    for (int kq = 0; kq < 2; kq++)
      ap[kq] = *(const short8*)(QPs + qrow * 64 + ((kq * 4 + quad) ^ (qrow & 7)) * 8);

    // ---- O += P V  (rows q = quad*4+reg, cols d = dn*16+l15) ----
    __builtin_amdgcn_s_setprio(1);
    #pragma unroll
    for (int dn = 0; dn < 4; dn++) {
      const int dr = dn * 16 + l15;
      #pragma unroll
      for (int kq = 0; kq < 2; kq++) {
        const short8 bv = *(const short8*)(Vrd + dr * 64 + ((kq * 4 + quad) ^ (dr & 7)) * 8);
        oacc[dn] = __builtin_amdgcn_mfma_f32_16x16x32_bf16(ap[kq], bv, oacc[dn], 0, 0, 0);
      }
    }
    __builtin_amdgcn_s_setprio(0);
  };

  for (int mt2 = 0; mt2 < 8; mt2 += 2) {
    {   // even step: compute (Ks0,Vt0); prefetch tile mt2+1 into (Ks1,Vt1)
      stageK(mt2 + 1, Ks1);
      uint4 n0 = *(const uint4*)(vsrc + (size_t)(mt2 + 1) * TSTRIDE);
      tilecomp(mt2, Ks0, Vt0);
      scatterV(n0, Vt1);
      __syncthreads();   // Ks1 DMA drained + Vt1 scatters visible
    }
    {   // odd step: compute (Ks1,Vt1); prefetch tile mt2+2 into (Ks0,Vt0)
      const bool more = (mt2 + 2) < 8;
      uint4 m0 = make_uint4(0, 0, 0, 0);
      if (more) {
        stageK(mt2 + 2, Ks0);
        m0 = *(const uint4*)(vsrc + (size_t)(mt2 + 2) * TSTRIDE);
      }
      tilecomp(mt2 + 1, Ks1, Vt1);
      if (more) scatterV(m0, Vt0);
      __syncthreads();
    }
  }

  // epilogue: O rows q = quad*4+reg, cols d = dn*16+l15
  const float inv = 1.f / runsum;          // for q = l15
  float iv[4];
  #pragma unroll
  for (int reg = 0; reg < 4; reg++)
    iv[reg] = __shfl(inv, (lane & 48) | (quad * 4 + reg));
  #pragma unroll
  for (int reg = 0; reg < 4; reg++) {
    const int q = q0 + w * 16 + quad * 4 + reg;
    unsigned short* op = QKV + (size_t)(q * L_ + l) * 2304 + h * 64;
    #pragma unroll
    for (int dn = 0; dn < 4; dn++)
      op[dn * 16 + l15] = f2bf(oacc[dn][reg] * iv[reg]);
  }
}

// ---------------------------------------------------------------------------
__global__ __launch_bounds__(256) void score_kernel(const unsigned short* __restrict__ X,
                                                    const float* __restrict__ em,
                                                    float* __restrict__ Sv) {
  const int j = blockIdx.x;
  const int t = threadIdx.x;
  __shared__ float red[4];
  float part = 0.f;
  for (int c = 0; c < 3; c++) {
    const int d = t + c * 256;
    const unsigned short* p = X + (size_t)j * L_ * D_ + d;
    float s = 0.f;
    for (int l = 0; l < L_; l++) s += bf2f(p[l * D_]);
    const float diff = s * (1.f / 64.f) - em[j * D_ + d];
    part += diff * diff;
  }
  const float tot = blockSum256(part, red);
  if (t == 0) Sv[j] = tot;
}

// ---------------------------------------------------------------------------
__global__ __launch_bounds__(256) void finalize_kernel(const float* __restrict__ Sv,
                                                       int* __restrict__ mi,
                                                       float* __restrict__ out) {
  const int t = threadIdx.x;
  if (t < B_) {
    const int nr = mi[MI_NRESP + t];
    float best = 3.0e38f; int bi = 0;
    for (int j = 0; j < nr; j++) {
      const float v = Sv[j];
      if (v < best) { best = v; bi = j; }
    }
    mi[MI_NODE + t] = bi + 1;
    int next = nr / 20; if (next < 1) next = 1;
    out[OUT_NTL + t] = (float)(1 + next);
  }
  if (t == 0) out[OUT_NEA] = 0.f;
  __syncthreads();
  for (int idx = t; idx < B_ * T_; idx += 256) {
    const int b = idx >> 5, tt = idx & 31;
    out[OUT_OH + idx] = (tt == 0 || tt == mi[MI_NODE + b]) ? 1.f : 0.f;
  }
}

// ---------------------------------------------------------------------------
__global__ __launch_bounds__(256) void maskout_kernel(const float* __restrict__ am,
                                                      const int* __restrict__ mi,
                                                      float* __restrict__ out) {
  const int idx = blockIdx.x * 256 + threadIdx.x;
  const int b = idx >> 11, rem = idx & 2047;
  const int tt = rem >> 6, l = rem & 63;
  const int node = mi[MI_NODE + b];
  out[OUT_EXT + idx] = (tt == 0 || tt == node) ? 1.f : 0.f;
  float nm;
  if (tt == 0)      nm = am[(b * T_) * L_ + l];
  else if (tt == 1) nm = am[(b * T_ + node) * L_ + l];
  else              nm = 0.f;
  out[OUT_NMSK + idx] = nm;
}

// ---------------------------------------------------------------------------
__global__ __launch_bounds__(192) void newemb_kernel(const float* __restrict__ emb,
                                                     const int* __restrict__ mi,
                                                     float* __restrict__ out) {
  const int blk = blockIdx.x;
  const int b = blk >> 11, rem = blk & 2047;
  const int tt = rem >> 6, l = rem & 63;
  const int srct = (tt == 1) ? mi[MI_NODE + b] : 0;
  const float4 v = ((const float4*)(emb + (size_t)((b * T_ + srct) * L_ + l) * D_))[threadIdx.x];
  float* dst = out + OUT_NEMB + (size_t)blk * D_ + threadIdx.x * 4;
  dst[0] = v.x; dst[1] = v.y; dst[2] = v.z; dst[3] = v.w;
}

// ===========================================================================
extern "C" void kernel_launch(void* const* d_in, const int* in_sizes, int n_in,
                              void* d_out, int out_size, void* d_ws, size_t ws_size,
                              hipStream_t stream) {
  (void)in_sizes; (void)n_in; (void)out_size; (void)ws_size;
  const int*   tl  = (const int*)d_in[0];
  const float* emb = (const float*)d_in[1];
  const float* am  = (const float*)d_in[2];
  const float* P[28];
  for (int i = 0; i < 28; i++) P[i] = (const float*)d_in[3 + i];

  float* wsf   = (float*)d_ws;
  int*   mi    = (int*)d_ws;
  float* bias2 = wsf + WS_BIAS2;
  float* emean = wsf + WS_EMEAN;
  float* Sv    = wsf + WS_S;
  unsigned short* Wst = (unsigned short*)(wsf + WS_WST);  // peW | pdW
  unsigned short* peW = Wst;
  unsigned short* pdW = Wst + 196608;
  float* peB   = wsf + PEB_F;
  unsigned short* BIG = (unsigned short*)(wsf + WS_BIG);
  unsigned short* Zs  = (unsigned short*)(wsf + WS_BIG);  // bf16 Z overlay
  float* out   = (float*)d_out;
  unsigned short* X    = (unsigned short*)(out + OUT_XSCR);   // bf16 residual
  unsigned short* WSTK = (unsigned short*)(out + OUT_WSTK);   // converted weights

  meta_kernel<<<1, 64, 0, stream>>>(tl, mi);
  // convert all layer weights up front (4 passes)
  for (int p = 0; p < 4; p++) {
    const float* const* q = P + (p >> 1) * 12;
    const int i = p & 1;
    w2bf4_kernel<<<WPASS / 1024, 256, 0, stream>>>(
        q[0] + (size_t)i * 3 * D_ * D_, q[2] + (size_t)i * D_ * D_,
        q[6] + (size_t)i * F_ * D_, q[8] + (size_t)i * D_ * F_,
        WSTK + (size_t)p * WPASS);
  }
  pepd_stage<<<385, 256, 0, stream>>>(P[24], P[25], P[26], peW, pdW, peB);
  gather_kernel<<<NP_ * L_, 192, 0, stream>>>(emb, am, mi, X, bias2);
  emean_kernel<<<NP_, 256, 0, stream>>>(X, emean);
  zerotail_kernel<<<NP_ * L_, 256, 0, stream>>>(mi, BIG);

  const int RTM = 128;   // max row tiles (M-tile 256)
  for (int s = 0; s < 2; s++) {
    const float* const* q = P + s * 12;
    for (int i = 0; i < 2; i++) {
      const unsigned short* WP = WSTK + (size_t)(s * 2 + i) * WPASS;
      // QKV: X -> BIG [rows, 2304]
      gemm_mfma<0, false><<<RTM * 18, 256, 0, stream>>>(
          X, D_, D_, WP, D_, q[1] + i * 3 * D_, BIG, 3 * D_, 18, mi);
      attn_kernel<<<L_ * H_ * 4, 512, 0, stream>>>(BIG, bias2, mi);
      // out-proj: O (Q cols of BIG, lda=2304) -> += X
      gemm_mfma<0, true><<<RTM * 6, 256, 0, stream>>>(
          BIG, 3 * D_, D_, WP + WSEG0, D_, q[3] + i * D_, X, D_, 6, mi);
      ln_kernel<<<NP_ * L_, 256, 0, stream>>>(X, q[4] + i * D_, q[5] + i * D_, mi);
      // FFN1: X -> hidden BIG [rows, 2048] (relu)
      gemm_mfma<1, false><<<RTM * 16, 256, 0, stream>>>(
          X, D_, D_, WP + WSEG0 + WSEG1, D_, q[7] + i * F_, BIG, F_, 16, mi);
      // FFN2: hidden -> += X
      gemm_mfma<0, true><<<RTM * 6, 256, 0, stream>>>(
          BIG, F_, F_, WP + WSEG0 + WSEG1 + WSEG2, F_, q[9] + i * D_, X, D_, 6, mi);
      ln_kernel<<<NP_ * L_, 256, 0, stream>>>(X, q[10] + i * D_, q[11] + i * D_, mi);
    }
    if (s == 0) {
      // z = tanh(h @ pe_w^T + pe_b) -> Zs bf16 [rows][256] (cols 100..255 = 0)
      gemm_mfma<2, false><<<RTM * 2, 256, 0, stream>>>(
          X, D_, D_, peW, D_, peB, Zs, 256, 2, mi);
      // zd = tanh(z @ pd_w^T + pd_b) -> X bf16 (decoder input)
      gemm_mfma<2, false><<<RTM * 6, 256, 0, stream>>>(
          Zs, 256, 256, pdW, 256, P[27], X, D_, 6, mi);
    }
  }

  score_kernel<<<NP_, 256, 0, stream>>>(X, emean, Sv);
  finalize_kernel<<<1, 256, 0, stream>>>(Sv, mi, out);
  maskout_kernel<<<128, 256, 0, stream>>>(am, mi, out);
  newemb_kernel<<<B_ * T_ * L_, 192, 0, stream>>>(emb, mi, out);
}

// Round 16
// 2520.772 us; speedup vs baseline: 1.1061x; 1.1061x over previous
//
#include <hip/hip_runtime.h>
#include <hip/hip_bf16.h>
#include <math.h>

// ============================================================================
// ResponseFilter — round 18: restore round-12 best (2574us, absmax 0).
//
// r13-r17 A/B'd every remaining GEMM structural knob (LDS epilogue, wave
// shape, buffer depth/occupancy, phase interleave, launch-bounds): all
// regressed vs r12. The barrier-synced GEMM family's optimum is r12's
// 256x128 tile / 512 thr / BK=32 triple-buffer / counted vmcnt(3) / raw
// barrier / interleaved stage-issue. Remaining headroom (MfmaUtil 27% vs
// m201's 62%) requires the full 8-phase 256^2 schedule — race-prone
// headlessly (m152/m232). This round restores r12 byte-identically.
// ============================================================================

#define B_  16
#define T_  32
#define L_  64
#define D_  768
#define H_  12
#define F_  2048
#define ZR_ 100
#define NP_ 512
#define EPS_ 1e-5f

// meta int offsets (d_ws as int*)
#define MI_NTOT  0
#define MI_NRESP 8
#define MI_OFF   32
#define MI_BIDX  64
#define MI_TIDX  576
#define MI_NODE  1088

// ws float offsets
#define WS_BIAS2 2048
#define WS_EMEAN 34816
#define WS_S     428032
#define WS_WST   428544    // pe/pd padded bf16 weights + padded pe bias
#define WS_BIG   1313280   // bf16 QKV/hidden region; bf16 Z overlay

#define PEB_F    (WS_WST + 196608)   // float offset of padded pe bias [256]

// d_out float offsets (flat tuple: oh[512], ext_mask[32768], n_ext_adv[1],
// new_tree_lens[16], new_emb[25165824], new_msk[32768])
#define OUT_OH   0
#define OUT_EXT  512
#define OUT_NEA  33280
#define OUT_NTL  33281
#define OUT_NEMB 33297
#define OUT_NMSK 25199121
#define OUT_XSCR 33300      // bf16 X scratch, 32768*768 ushorts (ends 12616212)
#define OUT_WSTK 12616224   // bf16 converted weights, 4 passes x 5,505,024 ushorts

// per-pass converted-weight segment sizes (ushorts)
#define WSEG0 1769472   // qkv  [2304][768]
#define WSEG1 589824    // out  [768][768]
#define WSEG2 1572864   // w1   [2048][768]
#define WSEG3 1572864   // w2   [768][2048]
#define WPASS 5505024

typedef __attribute__((ext_vector_type(8))) short short8;
typedef __attribute__((ext_vector_type(4))) float f32x4;

__device__ inline float bf2f(unsigned s) {
  return __uint_as_float((s & 0xffffu) << 16);
}
__device__ inline unsigned short f2bf(float x) {
  unsigned u = __float_as_uint(x);
  u += 0x7fffu + ((u >> 16) & 1u);      // round-to-nearest-even
  return (unsigned short)(u >> 16);
}
__device__ inline unsigned pack2(float a, float b) {
  return (unsigned)f2bf(a) | ((unsigned)f2bf(b) << 16);
}

// ---------------------------------------------------------------------------
__global__ void meta_kernel(const int* __restrict__ tl, int* __restrict__ mi) {
  if (threadIdx.x != 0) return;
  int off = 0;
  for (int b = 0; b < B_; b++) {
    int nr = tl[b] - 1;
    mi[MI_NRESP + b] = nr;
    mi[MI_OFF + b] = off;
    off += nr;
  }
  mi[MI_NTOT] = off;
  for (int j = 0; j < NP_; j++) {
    int b = -1, t = 0;
    if (j < off) {
      b = 0;
      while (b + 1 < B_ && j >= mi[MI_OFF + b + 1]) b++;
      t = j - mi[MI_OFF + b] + 1;
    }
    mi[MI_BIDX + j] = b;
    mi[MI_TIDX + j] = t;
  }
}

// ---------------------------------------------------------------------------
// batched fp32 -> bf16 conversion of one layer-pass's 4 weight matrices.
// grid = WPASS/1024 blocks; segment boundaries are multiples of 1024.
__global__ __launch_bounds__(256) void w2bf4_kernel(
    const float* __restrict__ s0, const float* __restrict__ s1,
    const float* __restrict__ s2, const float* __restrict__ s3,
    unsigned short* __restrict__ dst) {
  const int e = blockIdx.x * 1024 + threadIdx.x * 4;
  const float* src;
  int off;
  if (e < WSEG0)                         { src = s0; off = e; }
  else if (e < WSEG0 + WSEG1)            { src = s1; off = e - WSEG0; }
  else if (e < WSEG0 + WSEG1 + WSEG2)    { src = s2; off = e - WSEG0 - WSEG1; }
  else                                   { src = s3; off = e - WSEG0 - WSEG1 - WSEG2; }
  float4 v = *(const float4*)(src + off);
  uint2 pk; pk.x = pack2(v.x, v.y); pk.y = pack2(v.z, v.w);
  *(uint2*)(dst + e) = pk;
}

// ---------------------------------------------------------------------------
// pe_w [100][768] -> peW [256][768] bf16 (rows >=100 zero)
// pd_w [768][100] -> pdW [768][256] bf16 (cols >=100 zero)
// pe_b [100]      -> peB [256] fp32 (zero-padded)
__global__ __launch_bounds__(256) void pepd_stage(
    const float* __restrict__ pew, const float* __restrict__ peb,
    const float* __restrict__ pdw,
    unsigned short* __restrict__ dpe, unsigned short* __restrict__ dpd,
    float* __restrict__ dpeb) {
  const int blk = blockIdx.x, t = threadIdx.x;
  if (blk < 192) {                       // pe: 196608 elems
    const int e = blk * 1024 + t * 4;
    const int r = e / 768, c = e % 768;
    float v[4];
    #pragma unroll
    for (int j = 0; j < 4; j++) v[j] = (r < ZR_) ? pew[r * 768 + c + j] : 0.f;
    uint2 pk; pk.x = pack2(v[0], v[1]); pk.y = pack2(v[2], v[3]);
    *(uint2*)(dpe + e) = pk;
  } else if (blk < 384) {                // pd: 196608 elems
    const int e = (blk - 192) * 1024 + t * 4;
    const int r = e / 256, c = e % 256;
    float v[4];
    #pragma unroll
    for (int j = 0; j < 4; j++) v[j] = (c + j < ZR_) ? pdw[r * ZR_ + c + j] : 0.f;
    uint2 pk; pk.x = pack2(v[0], v[1]); pk.y = pack2(v[2], v[3]);
    *(uint2*)(dpd + e) = pk;
  } else {                               // bias pad
    dpeb[t] = (t < ZR_) ? peb[t] : 0.f;
  }
}

// ---------------------------------------------------------------------------
// X[j,l,:] bf16 = reply embedding (zero for padded j); bias2 = mask or -1e30
__global__ __launch_bounds__(192) void gather_kernel(
    const float* __restrict__ emb, const float* __restrict__ am,
    const int* __restrict__ mi, unsigned short* __restrict__ X,
    float* __restrict__ bias2) {
  const int blk = blockIdx.x;          // j*64 + l
  const int j = blk >> 6, l = blk & 63;
  const int ntot = mi[MI_NTOT];
  const int t = threadIdx.x;
  float4 v = make_float4(0.f, 0.f, 0.f, 0.f);
  if (j < ntot) {
    const int b = mi[MI_BIDX + j], tt = mi[MI_TIDX + j];
    v = ((const float4*)(emb + (size_t)((b * T_ + tt) * L_ + l) * D_))[t];
    if (t == 0) bias2[blk] = am[(b * T_ + tt) * L_ + l];
  } else {
    if (t == 0) bias2[blk] = -1e30f;
  }
  uint2 pk; pk.x = pack2(v.x, v.y); pk.y = pack2(v.z, v.w);
  *(uint2*)(X + (size_t)blk * D_ + t * 4) = pk;
}

// ---------------------------------------------------------------------------
// zero QKV rows >= ntot*64 in BIG (once per launch): attention reads K/V for
// all 512 padded responses; rows beyond the last GEMM tile must be finite.
__global__ __launch_bounds__(256) void zerotail_kernel(const int* __restrict__ mi,
                                                       unsigned short* __restrict__ BIG) {
  const int row = blockIdx.x;                 // 0 .. 32767
  if (row < mi[MI_NTOT] * 64) return;
  uint4 z = make_uint4(0u, 0u, 0u, 0u);
  uint4* p = (uint4*)(BIG + (size_t)row * 2304);   // 2304 ushorts = 288 uint4
  for (int c = threadIdx.x; c < 288; c += 256) p[c] = z;
}

// ---------------------------------------------------------------------------
__global__ __launch_bounds__(256) void emean_kernel(const unsigned short* __restrict__ X,
                                                    float* __restrict__ em) {
  const int j = blockIdx.x;
  int d = threadIdx.x;
  for (int c = 0; c < 3; c++, d += 256) {
    const unsigned short* p = X + (size_t)j * L_ * D_ + d;
    float s = 0.f;
    for (int l = 0; l < L_; l++) s += bf2f(p[l * D_]);
    em[j * D_ + d] = s * (1.f / 64.f);
  }
}

// ---------------------------------------------------------------------------
__device__ inline float blockSum256(float v, float* red) {
  #pragma unroll
  for (int o = 32; o > 0; o >>= 1) v += __shfl_down(v, o);
  const int lane = threadIdx.x & 63, wid = threadIdx.x >> 6;
  __syncthreads();
  if (lane == 0) red[wid] = v;
  __syncthreads();
  return red[0] + red[1] + red[2] + red[3];
}

// in-place LN (bf16 storage, fp32 stats); skips padded rows
__global__ __launch_bounds__(256) void ln_kernel(unsigned short* __restrict__ X,
                                                 const float* __restrict__ g,
                                                 const float* __restrict__ bb,
                                                 const int* __restrict__ mi) {
  const int row = blockIdx.x;
  if (row >= mi[MI_NTOT] * L_) return;
  unsigned short* p = X + (size_t)row * D_;
  const int t = threadIdx.x;
  __shared__ float red[4];
  float v0 = bf2f(p[t]), v1 = bf2f(p[t + 256]), v2 = bf2f(p[t + 512]);
  float s = blockSum256(v0 + v1 + v2, red);
  float m = s * (1.f / 768.f);
  float d0 = v0 - m, d1 = v1 - m, d2 = v2 - m;
  float q = blockSum256(d0 * d0 + d1 * d1 + d2 * d2, red);
  float r = rsqrtf(q * (1.f / 768.f) + EPS_);
  p[t]       = f2bf(d0 * r * g[t]       + bb[t]);
  p[t + 256] = f2bf(d1 * r * g[t + 256] + bb[t + 256]);
  p[t + 512] = f2bf(d2 * r * g[t + 512] + bb[t + 512]);
}

// ---------------------------------------------------------------------------
// MFMA bf16 GEMM: C[M,N] = [C +] act(A @ W^T + bias). 256x128 tile, 512 thr
// (8 waves 4Mx2N; wave = 64x64 via 4x4 of 16x16x32 MFMA), BK=32,
// TRIPLE-buffered LDS (72 KB -> 2 blocks/CU). Per kt: compute buf kt%3,
// stage tile kt+2 (3 gload_lds/thread: 2 A-halves + B) into buf (kt+2)%3,
// s_waitcnt vmcnt(3) (tile kt+1 only) + RAW s_barrier (no drain).
// Launch grid 128*CT (CT = N/128); ACTIVE tiles NTa = ceil(rows/256)*CT on
// device; bijective m204 chunk map over NTa (8 XCDs), col-fastest in chunk.
// LDS rows 32 ushorts; 16B group g of row at slot g^((row>>1)&3).
// ACT: 0 none, 1 relu, 2 tanh.
template <int ACT, bool ADD>
__global__ __launch_bounds__(512, 4) void gemm_mfma(
    const unsigned short* __restrict__ A, int lda, int K,
    const unsigned short* __restrict__ W, int ldw,
    const float* __restrict__ bias,
    unsigned short* __restrict__ C, int ldc, int CT,
    const int* __restrict__ mi) {
  const int rows = mi[MI_NTOT] * 64;
  const int RTa = (rows + 255) >> 8;
  const int NTa = RTa * CT;
  const int id = blockIdx.x;
  if (id >= NTa) return;
  // bijective XCD chunk map (m204): xcd k gets a contiguous wg range
  const int q8 = NTa >> 3, r8 = NTa & 7;
  const int xcd = id & 7, idx = id >> 3;
  const int wg = (xcd < r8 ? xcd * (q8 + 1) : r8 * (q8 + 1) + (xcd - r8) * q8) + idx;
  const int row0 = (wg / CT) * 256;
  const int col0 = (wg % CT) * 128;
  __shared__ unsigned short As[3][256 * 32];
  __shared__ unsigned short Bs[3][128 * 32];
  const int t = threadIdx.x;            // 0..511
  const int lane = t & 63, w = t >> 6;  // 8 waves
  const int wr = w >> 1, wc = w & 1;    // 4 x 2 wave grid
  const int quad = lane >> 4, l15 = lane & 15;

  // staging coords: A chunk c = ph*512 + t (ph 0..1): row = ph*128 + (t>>2),
  // slot = t&3; B chunk c = t: row = t>>2 (0..127). gs = slot^((row>>1)&3)
  // is ph-invariant (128 mod 4-row stripes aligned).
  const int srow = t >> 2;              // 0..127
  const int sgs = (t & 3) ^ ((srow >> 1) & 3);
  const unsigned short* aSrc = A + (size_t)(row0 + srow) * lda + sgs * 8;
  const unsigned short* bSrc = W + (size_t)(col0 + srow) * ldw + sgs * 8;

#define STAGE_(kk, Ad, Bd)                                                      \
  do {                                                                          \
    __builtin_amdgcn_global_load_lds(                                           \
        (const __attribute__((address_space(1))) void*)(aSrc + (kk)),           \
        (__attribute__((address_space(3))) void*)((Ad) + w * 512), 16, 0, 0);   \
    __builtin_amdgcn_global_load_lds(                                           \
        (const __attribute__((address_space(1))) void*)(aSrc + (size_t)128 * lda + (kk)), \
        (__attribute__((address_space(3))) void*)((Ad) + 4096 + w * 512), 16, 0, 0); \
    __builtin_amdgcn_global_load_lds(                                           \
        (const __attribute__((address_space(1))) void*)(bSrc + (kk)),           \
        (__attribute__((address_space(3))) void*)((Bd) + w * 512), 16, 0, 0);   \
  } while (0)

  auto LDA_ = [&](const unsigned short* buf, int m) -> short8 {
    const int ar = wr * 64 + m * 16 + l15;
    return *(const short8*)(buf + ar * 32 + (quad ^ ((ar >> 1) & 3)) * 8);
  };
  auto LDB_ = [&](const unsigned short* buf, int n) -> short8 {
    const int bn = wc * 64 + n * 16 + l15;
    return *(const short8*)(buf + bn * 32 + (quad ^ ((bn >> 1) & 3)) * 8);
  };

  f32x4 acc[4][4];
  #pragma unroll
  for (int m = 0; m < 4; m++)
    #pragma unroll
    for (int n = 0; n < 4; n++) acc[m][n] = (f32x4){0.f, 0.f, 0.f, 0.f};

  unsigned short* a0 = As[0]; unsigned short* a1 = As[1]; unsigned short* a2 = As[2];
  unsigned short* b0 = Bs[0]; unsigned short* b1 = Bs[1]; unsigned short* b2 = Bs[2];

  // prologue: stage tiles 0 and 1 (KT >= 3 at all call sites: K in {256,768,2048})
  STAGE_(0, a0, b0);
  STAGE_(32, a1, b1);
  __builtin_amdgcn_sched_barrier(0);
  asm volatile("s_waitcnt vmcnt(3)" ::: "memory");   // tile 0 landed; 1 in flight
  __builtin_amdgcn_sched_barrier(0);
  __builtin_amdgcn_s_barrier();
  __builtin_amdgcn_sched_barrier(0);

  const int KT = K >> 5;
  for (int kt = 0; kt < KT; ++kt) {
    const bool m2 = (kt + 2) < KT;
    const int kn = (kt + 2) << 5;
    short8 afr[4], bfr[4];

    #pragma unroll
    for (int n = 0; n < 4; n++) bfr[n] = LDB_(b0, n);
    #pragma unroll
    for (int m = 0; m < 4; m++) afr[m] = LDA_(a0, m);
    if (m2) STAGE_(kn, a2, b2);
    __builtin_amdgcn_s_setprio(1);
    #pragma unroll
    for (int m = 0; m < 4; m++)
      #pragma unroll
      for (int n = 0; n < 4; n++)
        acc[m][n] = __builtin_amdgcn_mfma_f32_16x16x32_bf16(afr[m], bfr[n], acc[m][n], 0, 0, 0);
    __builtin_amdgcn_s_setprio(0);

    if (kt + 1 < KT) {
      // wait tile kt+1 (issued a full iteration ago); kt+2 stays in flight.
      __builtin_amdgcn_sched_barrier(0);
      if (m2) asm volatile("s_waitcnt vmcnt(3)" ::: "memory");
      else    asm volatile("s_waitcnt vmcnt(0)" ::: "memory");
      __builtin_amdgcn_sched_barrier(0);
      __builtin_amdgcn_s_barrier();      // RAW barrier — no vmcnt drain
      __builtin_amdgcn_sched_barrier(0);
    }
    unsigned short* ta = a0; a0 = a1; a1 = a2; a2 = ta;
    unsigned short* tb = b0; b0 = b1; b1 = b2; b2 = tb;
  }
#undef STAGE_

  // epilogue: C/D layout col = lane&15, row = quad*4 + reg
  float bv[4];
  #pragma unroll
  for (int n = 0; n < 4; n++) bv[n] = bias[col0 + wc * 64 + n * 16 + l15];
  #pragma unroll
  for (int m = 0; m < 4; m++) {
    #pragma unroll
    for (int reg = 0; reg < 4; reg++) {
      const size_t cr = (size_t)(row0 + wr * 64 + m * 16 + quad * 4 + reg) * ldc;
      #pragma unroll
      for (int n = 0; n < 4; n++) {
        const int cn = col0 + wc * 64 + n * 16 + l15;
        float x = acc[m][n][reg] + bv[n];
        if (ACT == 1) x = fmaxf(x, 0.f);
        if (ACT == 2) x = tanhf(x);
        if (ADD) x += bf2f(C[cr + cn]);
        C[cr + cn] = f2bf(x);
      }
    }
  }
}

// ---------------------------------------------------------------------------
// Pipelined MFMA flash attention. 1-D grid 3072: id&7 = XCD, then ntp (0..3)
// fastest, lh-chunk slowest -> the blocks sharing one (l,h) K/V slice are
// L2-co-resident on one XCD. 512 threads / 8 waves; block owns 128 q rows;
// wave w owns q rows w*16..w*16+15. SWAPPED QK^T: sa = mfma(K,Q) -> lane
// owns q = l15 with 16 keys local; softmax = local tree + 2 shfl_xor;
// alpha/inv broadcast to oacc rows (q = quad*4+reg) via 4 shfl.
// K dbuf via global_load_lds; V dbuf via reg-staging scatter-late.
__global__ __launch_bounds__(512) void attn_kernel(
    unsigned short* __restrict__ QKV, const float* __restrict__ bias2,
    const int* __restrict__ mi) {
  const int ntot = mi[MI_NTOT];
  const int id = blockIdx.x;
  const int xcd = id & 7, rr = id >> 3;
  const int ntp = rr & 3, lhi = rr >> 2;       // lhi 0..95
  if (ntp * 128 >= ntot) return;
  const int lh = lhi * 8 + xcd;                // 0..767
  const int l = lh / H_, h = lh - l * H_;
  __shared__ unsigned short QPs[128 * 64];  // Q staging, then P (per-wave rows)
  __shared__ unsigned short Ks0[64 * 64], Ks1[64 * 64];
  __shared__ unsigned short Vt0[64 * 64], Vt1[64 * 64];  // V^T [d][key], swizzled
  __shared__ float Bls[512];
  const int t = threadIdx.x;
  const int lane = t & 63, w = t >> 6;      // 8 waves
  const int quad = lane >> 4, l15 = lane & 15;
  const int q0 = ntp * 128;
  const size_t TSTRIDE = (size_t)64 * L_ * 2304;   // elems per 64-key tile

  // K source (1 chunk/thread): row = t>>3 in [0,64), group swizzled
  const int krow = t >> 3;
  const int kgs = (t & 7) ^ (krow & 7);
  const unsigned short* ksrc =
      QKV + (size_t)(krow * L_ + l) * 2304 + 768 + h * 64 + kgs * 8;
  // V source (1 uint4/thread): d-group = w, key = lane
  const unsigned short* vsrc =
      QKV + (size_t)(lane * L_ + l) * 2304 + 1536 + h * 64 + w * 8;

  auto stageK = [&](int mt, unsigned short* Kw) {
    __builtin_amdgcn_global_load_lds(
        (const __attribute__((address_space(1))) void*)(ksrc + (size_t)mt * TSTRIDE),
        (__attribute__((address_space(3))) void*)(Kw + w * 512), 16, 0, 0);
  };
  auto scatterV = [&](uint4 a0, unsigned short* Vw) {
    const unsigned short* p0 = (const unsigned short*)&a0;
    #pragma unroll
    for (int j = 0; j < 8; j++) {
      const int d = w * 8 + j;
      Vw[d * 64 + ((lane >> 3) ^ (d & 7)) * 8 + (lane & 7)] = p0[j];
    }
  };

  // prologue: stage Q (2 chunks/thread) + K0, V0 -> regs, bias -> LDS
  #pragma unroll
  for (int r = 0; r < 2; r++) {
    const int c = r * 512 + t;
    const int row = c >> 3, g = c & 7, gs = g ^ (row & 7);
    const unsigned short* gq =
        QKV + (size_t)((q0 + row) * L_ + l) * 2304 + h * 64 + gs * 8;
    __builtin_amdgcn_global_load_lds(
        (const __attribute__((address_space(1))) void*)gq,
        (__attribute__((address_space(3))) void*)(QPs + r * 4096 + w * 512), 16, 0, 0);
  }
  stageK(0, Ks0);
  uint4 pv0 = *(const uint4*)vsrc;
  Bls[t] = bias2[t * 64 + l];
  __syncthreads();                       // Q,K0 in LDS; pv0 in regs

  // Q fragments (loop-invariant), used as the MFMA B-operand (col = l15)
  const int qrow = w * 16 + l15;         // 0..127
  short8 aq[2];
  #pragma unroll
  for (int kq = 0; kq < 2; kq++)
    aq[kq] = *(const short8*)(QPs + qrow * 64 + ((kq * 4 + quad) ^ (qrow & 7)) * 8);
  scatterV(pv0, Vt0);
  __syncthreads();                       // Vt0 visible; aq read before P reuse

  float runmax = -3.0e38f, runsum = 0.f;
  f32x4 oacc[4];
  #pragma unroll
  for (int i = 0; i < 4; i++) oacc[i] = (f32x4){0.f, 0.f, 0.f, 0.f};

  auto tilecomp = [&](int mt, const unsigned short* Krd, const unsigned short* Vrd) {
    // ---- S^T = K Q^T : sa[n][reg] = S[key=n*16+quad*4+reg][q=l15] ----
    f32x4 sa[4];
    #pragma unroll
    for (int n = 0; n < 4; n++) sa[n] = (f32x4){0.f, 0.f, 0.f, 0.f};
    __builtin_amdgcn_s_setprio(1);
    #pragma unroll
    for (int n = 0; n < 4; n++) {
      const int kr = n * 16 + l15;
      #pragma unroll
      for (int kq = 0; kq < 2; kq++) {
        const short8 bk = *(const short8*)(Krd + kr * 64 + ((kq * 4 + quad) ^ (kr & 7)) * 8);
        sa[n] = __builtin_amdgcn_mfma_f32_16x16x32_bf16(bk, aq[kq], sa[n], 0, 0, 0);
      }
    }
    __builtin_amdgcn_s_setprio(0);
    // bias by key: float4 per n (keys n*16 + quad*4 + 0..3)
    #pragma unroll
    for (int n = 0; n < 4; n++) {
      const float4 bj = *(const float4*)(Bls + mt * 64 + n * 16 + quad * 4);
      sa[n][0] = sa[n][0] * 0.125f + bj.x;
      sa[n][1] = sa[n][1] * 0.125f + bj.y;
      sa[n][2] = sa[n][2] * 0.125f + bj.z;
      sa[n][3] = sa[n][3] * 0.125f + bj.w;
    }

    // ---- online softmax for q = l15: local 16-key tree + 2 shfl ----
    float m16 = -3.0e38f;
    #pragma unroll
    for (int n = 0; n < 4; n++)
      m16 = fmaxf(m16, fmaxf(fmaxf(sa[n][0], sa[n][1]), fmaxf(sa[n][2], sa[n][3])));
    m16 = fmaxf(m16, __shfl_xor(m16, 16));
    m16 = fmaxf(m16, __shfl_xor(m16, 32));
    const float nm = fmaxf(runmax, m16);
    const float alpha = __expf(runmax - nm);
    runmax = nm;
    float s16 = 0.f;
    #pragma unroll
    for (int n = 0; n < 4; n++)
      #pragma unroll
      for (int reg = 0; reg < 4; reg++) {
        const float p = __expf(sa[n][reg] - nm);
        sa[n][reg] = p; s16 += p;
      }
    s16 += __shfl_xor(s16, 16);
    s16 += __shfl_xor(s16, 32);
    runsum = runsum * alpha + s16;
    // broadcast alpha to oacc rows q = quad*4+reg (src lane l15 = that q)
    float al[4];
    #pragma unroll
    for (int reg = 0; reg < 4; reg++)
      al[reg] = __shfl(alpha, (lane & 48) | (quad * 4 + reg));
    #pragma unroll
    for (int dn = 0; dn < 4; dn++)
      #pragma unroll
      for (int reg = 0; reg < 4; reg++) oacc[dn][reg] *= al[reg];

    // ---- P -> LDS bf16 (row qrow = w*16+l15, wave-private) ----
    #pragma unroll
    for (int n = 0; n < 4; n++)
      #pragma unroll
      for (int reg = 0; reg < 4; reg++) {
        const int key = n * 16 + quad * 4 + reg;
        QPs[qrow * 64 + ((key >> 3) ^ (qrow & 7)) * 8 + (key & 7)] = f2bf(sa[n][reg]);
      }
    short8 ap[2];
    #pragma unroll
    for (int kq = 0; kq < 2; kq++)
      ap[kq] = *(const short8*)(QPs + qrow * 64 + ((kq * 4 + quad) ^ (qrow & 7)) * 8);

    // ---- O += P V  (rows q = quad*4+reg, cols d = dn*16+l15) ----
    __builtin_amdgcn_s_setprio(1);
    #pragma unroll
    for (int dn = 0; dn < 4; dn++) {
      const int dr = dn * 16 + l15;
      #pragma unroll
      for (int kq = 0; kq < 2; kq++) {
        const short8 bv = *(const short8*)(Vrd + dr * 64 + ((kq * 4 + quad) ^ (dr & 7)) * 8);
        oacc[dn] = __builtin_amdgcn_mfma_f32_16x16x32_bf16(ap[kq], bv, oacc[dn], 0, 0, 0);
      }
    }
    __builtin_amdgcn_s_setprio(0);
  };

  for (int mt2 = 0; mt2 < 8; mt2 += 2) {
    {   // even step: compute (Ks0,Vt0); prefetch tile mt2+1 into (Ks1,Vt1)
      stageK(mt2 + 1, Ks1);
      uint4 n0 = *(const uint4*)(vsrc + (size_t)(mt2 + 1) * TSTRIDE);
      tilecomp(mt2, Ks0, Vt0);
      scatterV(n0, Vt1);
      __syncthreads();   // Ks1 DMA drained + Vt1 scatters visible
    }
    {   // odd step: compute (Ks1,Vt1); prefetch tile mt2+2 into (Ks0,Vt0)
      const bool more = (mt2 + 2) < 8;
      uint4 m0 = make_uint4(0, 0, 0, 0);
      if (more) {
        stageK(mt2 + 2, Ks0);
        m0 = *(const uint4*)(vsrc + (size_t)(mt2 + 2) * TSTRIDE);
      }
      tilecomp(mt2 + 1, Ks1, Vt1);
      if (more) scatterV(m0, Vt0);
      __syncthreads();
    }
  }

  // epilogue: O rows q = quad*4+reg, cols d = dn*16+l15
  const float inv = 1.f / runsum;          // for q = l15
  float iv[4];
  #pragma unroll
  for (int reg = 0; reg < 4; reg++)
    iv[reg] = __shfl(inv, (lane & 48) | (quad * 4 + reg));
  #pragma unroll
  for (int reg = 0; reg < 4; reg++) {
    const int q = q0 + w * 16 + quad * 4 + reg;
    unsigned short* op = QKV + (size_t)(q * L_ + l) * 2304 + h * 64;
    #pragma unroll
    for (int dn = 0; dn < 4; dn++)
      op[dn * 16 + l15] = f2bf(oacc[dn][reg] * iv[reg]);
  }
}

// ---------------------------------------------------------------------------
__global__ __launch_bounds__(256) void score_kernel(const unsigned short* __restrict__ X,
                                                    const float* __restrict__ em,
                                                    float* __restrict__ Sv) {
  const int j = blockIdx.x;
  const int t = threadIdx.x;
  __shared__ float red[4];
  float part = 0.f;
  for (int c = 0; c < 3; c++) {
    const int d = t + c * 256;
    const unsigned short* p = X + (size_t)j * L_ * D_ + d;
    float s = 0.f;
    for (int l = 0; l < L_; l++) s += bf2f(p[l * D_]);
    const float diff = s * (1.f / 64.f) - em[j * D_ + d];
    part += diff * diff;
  }
  const float tot = blockSum256(part, red);
  if (t == 0) Sv[j] = tot;
}

// ---------------------------------------------------------------------------
__global__ __launch_bounds__(256) void finalize_kernel(const float* __restrict__ Sv,
                                                       int* __restrict__ mi,
                                                       float* __restrict__ out) {
  const int t = threadIdx.x;
  if (t < B_) {
    const int nr = mi[MI_NRESP + t];
    float best = 3.0e38f; int bi = 0;
    for (int j = 0; j < nr; j++) {
      const float v = Sv[j];
      if (v < best) { best = v; bi = j; }
    }
    mi[MI_NODE + t] = bi + 1;
    int next = nr / 20; if (next < 1) next = 1;
    out[OUT_NTL + t] = (float)(1 + next);
  }
  if (t == 0) out[OUT_NEA] = 0.f;
  __syncthreads();
  for (int idx = t; idx < B_ * T_; idx += 256) {
    const int b = idx >> 5, tt = idx & 31;
    out[OUT_OH + idx] = (tt == 0 || tt == mi[MI_NODE + b]) ? 1.f : 0.f;
  }
}

// ---------------------------------------------------------------------------
__global__ __launch_bounds__(256) void maskout_kernel(const float* __restrict__ am,
                                                      const int* __restrict__ mi,
                                                      float* __restrict__ out) {
  const int idx = blockIdx.x * 256 + threadIdx.x;
  const int b = idx >> 11, rem = idx & 2047;
  const int tt = rem >> 6, l = rem & 63;
  const int node = mi[MI_NODE + b];
  out[OUT_EXT + idx] = (tt == 0 || tt == node) ? 1.f : 0.f;
  float nm;
  if (tt == 0)      nm = am[(b * T_) * L_ + l];
  else if (tt == 1) nm = am[(b * T_ + node) * L_ + l];
  else              nm = 0.f;
  out[OUT_NMSK + idx] = nm;
}

// ---------------------------------------------------------------------------
__global__ __launch_bounds__(192) void newemb_kernel(const float* __restrict__ emb,
                                                     const int* __restrict__ mi,
                                                     float* __restrict__ out) {
  const int blk = blockIdx.x;
  const int b = blk >> 11, rem = blk & 2047;
  const int tt = rem >> 6, l = rem & 63;
  const int srct = (tt == 1) ? mi[MI_NODE + b] : 0;
  const float4 v = ((const float4*)(emb + (size_t)((b * T_ + srct) * L_ + l) * D_))[threadIdx.x];
  float* dst = out + OUT_NEMB + (size_t)blk * D_ + threadIdx.x * 4;
  dst[0] = v.x; dst[1] = v.y; dst[2] = v.z; dst[3] = v.w;
}

// ===========================================================================
extern "C" void kernel_launch(void* const* d_in, const int* in_sizes, int n_in,
                              void* d_out, int out_size, void* d_ws, size_t ws_size,
                              hipStream_t stream) {
  (void)in_sizes; (void)n_in; (void)out_size; (void)ws_size;
  const int*   tl  = (const int*)d_in[0];
  const float* emb = (const float*)d_in[1];
  const float* am  = (const float*)d_in[2];
  const float* P[28];
  for (int i = 0; i < 28; i++) P[i] = (const float*)d_in[3 + i];

  float* wsf   = (float*)d_ws;
  int*   mi    = (int*)d_ws;
  float* bias2 = wsf + WS_BIAS2;
  float* emean = wsf + WS_EMEAN;
  float* Sv    = wsf + WS_S;
  unsigned short* Wst = (unsigned short*)(wsf + WS_WST);  // peW | pdW
  unsigned short* peW = Wst;
  unsigned short* pdW = Wst + 196608;
  float* peB   = wsf + PEB_F;
  unsigned short* BIG = (unsigned short*)(wsf + WS_BIG);
  unsigned short* Zs  = (unsigned short*)(wsf + WS_BIG);  // bf16 Z overlay
  float* out   = (float*)d_out;
  unsigned short* X    = (unsigned short*)(out + OUT_XSCR);   // bf16 residual
  unsigned short* WSTK = (unsigned short*)(out + OUT_WSTK);   // converted weights

  meta_kernel<<<1, 64, 0, stream>>>(tl, mi);
  // convert all layer weights up front (4 passes)
  for (int p = 0; p < 4; p++) {
    const float* const* q = P + (p >> 1) * 12;
    const int i = p & 1;
    w2bf4_kernel<<<WPASS / 1024, 256, 0, stream>>>(
        q[0] + (size_t)i * 3 * D_ * D_, q[2] + (size_t)i * D_ * D_,
        q[6] + (size_t)i * F_ * D_, q[8] + (size_t)i * D_ * F_,
        WSTK + (size_t)p * WPASS);
  }
  pepd_stage<<<385, 256, 0, stream>>>(P[24], P[25], P[26], peW, pdW, peB);
  gather_kernel<<<NP_ * L_, 192, 0, stream>>>(emb, am, mi, X, bias2);
  emean_kernel<<<NP_, 256, 0, stream>>>(X, emean);
  zerotail_kernel<<<NP_ * L_, 256, 0, stream>>>(mi, BIG);

  const int RTM = 128;   // max row tiles (M-tile 256)
  for (int s = 0; s < 2; s++) {
    const float* const* q = P + s * 12;
    for (int i = 0; i < 2; i++) {
      const unsigned short* WP = WSTK + (size_t)(s * 2 + i) * WPASS;
      // QKV: X -> BIG [rows, 2304]
      gemm_mfma<0, false><<<RTM * 18, 512, 0, stream>>>(
          X, D_, D_, WP, D_, q[1] + i * 3 * D_, BIG, 3 * D_, 18, mi);
      attn_kernel<<<L_ * H_ * 4, 512, 0, stream>>>(BIG, bias2, mi);
      // out-proj: O (Q cols of BIG, lda=2304) -> += X
      gemm_mfma<0, true><<<RTM * 6, 512, 0, stream>>>(
          BIG, 3 * D_, D_, WP + WSEG0, D_, q[3] + i * D_, X, D_, 6, mi);
      ln_kernel<<<NP_ * L_, 256, 0, stream>>>(X, q[4] + i * D_, q[5] + i * D_, mi);
      // FFN1: X -> hidden BIG [rows, 2048] (relu)
      gemm_mfma<1, false><<<RTM * 16, 512, 0, stream>>>(
          X, D_, D_, WP + WSEG0 + WSEG1, D_, q[7] + i * F_, BIG, F_, 16, mi);
      // FFN2: hidden -> += X
      gemm_mfma<0, true><<<RTM * 6, 512, 0, stream>>>(
          BIG, F_, F_, WP + WSEG0 + WSEG1 + WSEG2, F_, q[9] + i * D_, X, D_, 6, mi);
      ln_kernel<<<NP_ * L_, 256, 0, stream>>>(X, q[10] + i * D_, q[11] + i * D_, mi);
    }
    if (s == 0) {
      // z = tanh(h @ pe_w^T + pe_b) -> Zs bf16 [rows][256] (cols 100..255 = 0)
      gemm_mfma<2, false><<<RTM * 2, 512, 0, stream>>>(
          X, D_, D_, peW, D_, peB, Zs, 256, 2, mi);
      // zd = tanh(z @ pd_w^T + pd_b) -> X bf16 (decoder input)
      gemm_mfma<2, false><<<RTM * 6, 512, 0, stream>>>(
          Zs, 256, 256, pdW, 256, P[27], X, D_, 6, mi);
    }
  }

  score_kernel<<<NP_, 256, 0, stream>>>(X, emean, Sv);
  finalize_kernel<<<1, 256, 0, stream>>>(Sv, mi, out);
  maskout_kernel<<<128, 256, 0, stream>>>(am, mi, out);
  newemb_kernel<<<B_ * T_ * L_, 192, 0, stream>>>(emb, mi, out);
}